// Round 1
// baseline (128.200 us; speedup 1.0000x reference)
//
#include <hip/hip_runtime.h>
#include <math.h>

// Problem constants (from setup_inputs)
#define BATCH 16
#define NP1   10001
#define KNN   16
#define DIM   128
#define NEG_INF_F (-1e9f)

// ---------------------------------------------------------------------------
// Kernel 1: per-node score.
// One wave (64 lanes) per node. Lane i holds float2 = elements [2i, 2i+1] of
// the D=128 row. Interference uses sum-then-dot: sum the 16 gathered neighbor
// vectors in registers, then one dot with psi[b,n]. Two values ({ctx, interf})
// reduced across the wave with 6 shfl_xor steps.
// ---------------------------------------------------------------------------
__global__ __launch_bounds__(256) void hs_scores_kernel(
    const float* __restrict__ query,      // [B, D]
    const float* __restrict__ psi,        // [B, NP1, D]
    const int*   __restrict__ knn,        // [B, NP1, K]
    const unsigned char* __restrict__ mask, // [B, NP1] (bool)
    const float* __restrict__ cur,        // [B, 2]
    const float* __restrict__ coords,     // [B, NP1, 2]
    const float* __restrict__ demands,    // [B, NP1]
    const float* __restrict__ lam_p,
    const float* __restrict__ mu_p,
    const float* __restrict__ nu_p,
    float* __restrict__ out)              // [B, NP1] scores (pre-softmax)
{
    const int wave_in_block = threadIdx.x >> 6;
    const int lane          = threadIdx.x & 63;
    const long node = (long)blockIdx.x * 4 + wave_in_block;
    if (node >= (long)BATCH * NP1) return;
    const int b = (int)(node / NP1);
    const int n = (int)(node % NP1);
    const long bn = (long)b * NP1 + n;

    // own row + query fragment
    const float2* prow = (const float2*)(psi + bn * DIM);
    const float2  p    = prow[lane];
    const float2* qrow = (const float2*)(query + (long)b * DIM);
    const float2  q    = qrow[lane];
    float ctx = p.x * q.x + p.y * q.y;

    // gather 16 neighbor rows; sum vectors first (sum-then-dot)
    const int* kptr = knn + bn * KNN;
    const float2* pbase = (const float2*)(psi + (long)b * NP1 * DIM);
    float2 nsum = make_float2(0.f, 0.f);
#pragma unroll
    for (int kk = 0; kk < KNN; ++kk) {
        const int idx = kptr[kk];                       // wave-uniform scalar load
        const float2 nb = pbase[(long)idx * (DIM / 2) + lane]; // 512B coalesced
        nsum.x += nb.x;
        nsum.y += nb.y;
    }
    float interf = p.x * nsum.x + p.y * nsum.y;

    // wave reduction of {ctx, interf}
#pragma unroll
    for (int off = 32; off > 0; off >>= 1) {
        ctx    += __shfl_xor(ctx, off, 64);
        interf += __shfl_xor(interf, off, 64);
    }

    if (lane == 0) {
        const float lam = fminf(fmaxf(lam_p[0], -2.f), 3.f);
        const float mu  = fminf(fmaxf(mu_p[0],   0.f), 20.f);
        const float nu  = fminf(fmaxf(nu_p[0],  -2.f), 3.f);
        const float dx = coords[bn * 2 + 0] - cur[b * 2 + 0];
        const float dy = coords[bn * 2 + 1] - cur[b * 2 + 1];
        const float dist = sqrtf(dx * dx + dy * dy);
        float s = ctx + lam * interf - mu * dist + nu * demands[bn];
        if (mask[bn]) s = NEG_INF_F;
        out[bn] = s;
    }
}

// ---------------------------------------------------------------------------
// Kernel 2: in-place log_softmax per batch row (10001 elements).
// One block of 1024 threads per batch row; each thread owns up to 10 elements
// held in registers across the two reduction passes.
// ---------------------------------------------------------------------------
#define LSM_THREADS 1024
#define LSM_ITERS   10   // ceil(10001 / 1024)

__global__ __launch_bounds__(LSM_THREADS) void hs_lsm_kernel(float* __restrict__ out)
{
    const int b = blockIdx.x;
    float* row = out + (long)b * NP1;
    const int lane = threadIdx.x & 63;
    const int wid  = threadIdx.x >> 6;

    float v[LSM_ITERS];
    float mx = -INFINITY;
#pragma unroll
    for (int i = 0; i < LSM_ITERS; ++i) {
        const int idx = threadIdx.x + i * LSM_THREADS;
        v[i] = (idx < NP1) ? row[idx] : -INFINITY;
        mx = fmaxf(mx, v[i]);
    }

    __shared__ float red_max[16];
    __shared__ float red_sum[16];

    // block max
#pragma unroll
    for (int off = 32; off > 0; off >>= 1) mx = fmaxf(mx, __shfl_xor(mx, off, 64));
    if (lane == 0) red_max[wid] = mx;
    __syncthreads();
    if (wid == 0) {
        float m = (lane < 16) ? red_max[lane] : -INFINITY;
#pragma unroll
        for (int off = 8; off > 0; off >>= 1) m = fmaxf(m, __shfl_xor(m, off, 64));
        if (lane == 0) red_max[0] = m;
    }
    __syncthreads();
    mx = red_max[0];

    // block sum of exp(v - mx)
    float sum = 0.f;
#pragma unroll
    for (int i = 0; i < LSM_ITERS; ++i) {
        const int idx = threadIdx.x + i * LSM_THREADS;
        if (idx < NP1) sum += expf(v[i] - mx);
    }
#pragma unroll
    for (int off = 32; off > 0; off >>= 1) sum += __shfl_xor(sum, off, 64);
    if (lane == 0) red_sum[wid] = sum;
    __syncthreads();
    if (wid == 0) {
        float s = (lane < 16) ? red_sum[lane] : 0.f;
#pragma unroll
        for (int off = 8; off > 0; off >>= 1) s += __shfl_xor(s, off, 64);
        if (lane == 0) red_sum[0] = s;
    }
    __syncthreads();
    const float lse = mx + logf(red_sum[0]);

#pragma unroll
    for (int i = 0; i < LSM_ITERS; ++i) {
        const int idx = threadIdx.x + i * LSM_THREADS;
        if (idx < NP1) row[idx] = v[i] - lse;
    }
}

// ---------------------------------------------------------------------------
extern "C" void kernel_launch(void* const* d_in, const int* in_sizes, int n_in,
                              void* d_out, int out_size, void* d_ws, size_t ws_size,
                              hipStream_t stream) {
    (void)in_sizes; (void)n_in; (void)d_ws; (void)ws_size; (void)out_size;

    const float* query   = (const float*)d_in[0];
    const float* psi     = (const float*)d_in[1];
    const int*   knn     = (const int*)d_in[2];
    const unsigned char* mask = (const unsigned char*)d_in[3];
    const float* cur     = (const float*)d_in[4];
    const float* coords  = (const float*)d_in[5];
    const float* demands = (const float*)d_in[6];
    const float* lam_p   = (const float*)d_in[7];
    const float* mu_p    = (const float*)d_in[8];
    const float* nu_p    = (const float*)d_in[9];
    float* out = (float*)d_out;

    const long total_nodes = (long)BATCH * NP1;        // 160016
    const int  blocks = (int)((total_nodes + 3) / 4);  // 4 waves/block, 1 node/wave

    hipLaunchKernelGGL(hs_scores_kernel, dim3(blocks), dim3(256), 0, stream,
                       query, psi, knn, mask, cur, coords, demands,
                       lam_p, mu_p, nu_p, out);

    hipLaunchKernelGGL(hs_lsm_kernel, dim3(BATCH), dim3(LSM_THREADS), 0, stream, out);
}

// Round 2
// 107.350 us; speedup vs baseline: 1.1942x; 1.1942x over previous
//
#include <hip/hip_runtime.h>
#include <math.h>

// Problem constants (from setup_inputs)
#define BATCH 16
#define NP1   10001
#define KNN   16
#define DIM   128
#define NEG_INF_F (-1e9f)

// ---------------------------------------------------------------------------
// Kernel 1: per-node score, MLP-maximized gather.
// One wave (64 lanes) per node. float4 granularity: 32 lanes cover one 512B
// row. Lanes 0-31 gather even-k neighbors, lanes 32-63 odd-k neighbors.
// All 8 gather loads issued before any accumulation (explicit nb[8] array)
// so the wave has 8 x 512B in flight -> hides L2/L3 latency.
// ---------------------------------------------------------------------------
__global__ __launch_bounds__(256) void hs_scores_kernel(
    const float* __restrict__ query,      // [B, D]
    const float* __restrict__ psi,        // [B, NP1, D]
    const int*   __restrict__ knn,        // [B, NP1, K]
    const unsigned char* __restrict__ mask, // [B, NP1] (bool)
    const float* __restrict__ cur,        // [B, 2]
    const float* __restrict__ coords,     // [B, NP1, 2]
    const float* __restrict__ demands,    // [B, NP1]
    const float* __restrict__ lam_p,
    const float* __restrict__ mu_p,
    const float* __restrict__ nu_p,
    float* __restrict__ out)              // [B, NP1] scores (pre-softmax)
{
    const int wid  = threadIdx.x >> 6;
    const int lane = threadIdx.x & 63;
    const int half = lane >> 5;           // 0: even-k, 1: odd-k
    const int l32  = lane & 31;
    const long node = (long)blockIdx.x * 4 + wid;   // == b*NP1 + n (flat)
    if (node >= (long)BATCH * NP1) return;
    const int b = (int)(node / NP1);

    const float4* psi4 = (const float4*)psi;
    const float4* gb   = psi4 + (long)b * NP1 * (DIM / 4);   // batch slab base

    // own row + query fragment (duplicated across the two half-waves)
    const float4 p = psi4[node * (DIM / 4) + l32];
    const float4 q = ((const float4*)query)[(long)b * (DIM / 4) + l32];
    float ctx = p.x * q.x + p.y * q.y + p.z * q.z + p.w * q.w;  // counted twice

    // neighbor indices: int2 per iteration, half-wave selects even/odd member
    const int2* kp2 = (const int2*)(knn + node * KNN);
    int idxs[KNN / 2];
#pragma unroll
    for (int t = 0; t < KNN / 2; ++t) {
        const int2 pr = kp2[t];
        idxs[t] = half ? pr.y : pr.x;
    }

    // issue all 8 gathers before consuming any (8 x 512B in flight)
    float4 nb[KNN / 2];
#pragma unroll
    for (int t = 0; t < KNN / 2; ++t)
        nb[t] = gb[(long)idxs[t] * (DIM / 4) + l32];

    // tree-sum the 8 neighbor fragments
    float4 s0, s1, s2, s3;
    s0.x = nb[0].x + nb[1].x; s0.y = nb[0].y + nb[1].y; s0.z = nb[0].z + nb[1].z; s0.w = nb[0].w + nb[1].w;
    s1.x = nb[2].x + nb[3].x; s1.y = nb[2].y + nb[3].y; s1.z = nb[2].z + nb[3].z; s1.w = nb[2].w + nb[3].w;
    s2.x = nb[4].x + nb[5].x; s2.y = nb[4].y + nb[5].y; s2.z = nb[4].z + nb[5].z; s2.w = nb[4].w + nb[5].w;
    s3.x = nb[6].x + nb[7].x; s3.y = nb[6].y + nb[7].y; s3.z = nb[6].z + nb[7].z; s3.w = nb[6].w + nb[7].w;
    s0.x += s1.x; s0.y += s1.y; s0.z += s1.z; s0.w += s1.w;
    s2.x += s3.x; s2.y += s3.y; s2.z += s3.z; s2.w += s3.w;
    s0.x += s2.x; s0.y += s2.y; s0.z += s2.z; s0.w += s2.w;

    float interf = p.x * s0.x + p.y * s0.y + p.z * s0.z + p.w * s0.w;

    // wave reduction of {ctx, interf}; halves of ctx are duplicates, interf
    // halves are the even-k / odd-k partial sums (both want a full 64-lane sum)
#pragma unroll
    for (int off = 32; off > 0; off >>= 1) {
        ctx    += __shfl_xor(ctx, off, 64);
        interf += __shfl_xor(interf, off, 64);
    }

    if (lane == 0) {
        const float lam = fminf(fmaxf(lam_p[0], -2.f), 3.f);
        const float mu  = fminf(fmaxf(mu_p[0],   0.f), 20.f);
        const float nu  = fminf(fmaxf(nu_p[0],  -2.f), 3.f);
        const float dx = coords[node * 2 + 0] - cur[b * 2 + 0];
        const float dy = coords[node * 2 + 1] - cur[b * 2 + 1];
        const float dist = sqrtf(dx * dx + dy * dy);
        float s = 0.5f * ctx + lam * interf - mu * dist + nu * demands[node];
        if (mask[node]) s = NEG_INF_F;
        out[node] = s;
    }
}

// ---------------------------------------------------------------------------
// Kernel 2: in-place log_softmax per batch row (10001 elements).
// One block of 1024 threads per batch row.
// ---------------------------------------------------------------------------
#define LSM_THREADS 1024
#define LSM_ITERS   10   // ceil(10001 / 1024)

__global__ __launch_bounds__(LSM_THREADS) void hs_lsm_kernel(float* __restrict__ out)
{
    const int b = blockIdx.x;
    float* row = out + (long)b * NP1;
    const int lane = threadIdx.x & 63;
    const int wid  = threadIdx.x >> 6;

    float v[LSM_ITERS];
    float mx = -INFINITY;
#pragma unroll
    for (int i = 0; i < LSM_ITERS; ++i) {
        const int idx = threadIdx.x + i * LSM_THREADS;
        v[i] = (idx < NP1) ? row[idx] : -INFINITY;
        mx = fmaxf(mx, v[i]);
    }

    __shared__ float red_max[16];
    __shared__ float red_sum[16];

#pragma unroll
    for (int off = 32; off > 0; off >>= 1) mx = fmaxf(mx, __shfl_xor(mx, off, 64));
    if (lane == 0) red_max[wid] = mx;
    __syncthreads();
    if (wid == 0) {
        float m = (lane < 16) ? red_max[lane] : -INFINITY;
#pragma unroll
        for (int off = 8; off > 0; off >>= 1) m = fmaxf(m, __shfl_xor(m, off, 64));
        if (lane == 0) red_max[0] = m;
    }
    __syncthreads();
    mx = red_max[0];

    float sum = 0.f;
#pragma unroll
    for (int i = 0; i < LSM_ITERS; ++i) {
        const int idx = threadIdx.x + i * LSM_THREADS;
        if (idx < NP1) sum += expf(v[i] - mx);
    }
#pragma unroll
    for (int off = 32; off > 0; off >>= 1) sum += __shfl_xor(sum, off, 64);
    if (lane == 0) red_sum[wid] = sum;
    __syncthreads();
    if (wid == 0) {
        float s = (lane < 16) ? red_sum[lane] : 0.f;
#pragma unroll
        for (int off = 8; off > 0; off >>= 1) s += __shfl_xor(s, off, 64);
        if (lane == 0) red_sum[0] = s;
    }
    __syncthreads();
    const float lse = mx + logf(red_sum[0]);

#pragma unroll
    for (int i = 0; i < LSM_ITERS; ++i) {
        const int idx = threadIdx.x + i * LSM_THREADS;
        if (idx < NP1) row[idx] = v[i] - lse;
    }
}

// ---------------------------------------------------------------------------
extern "C" void kernel_launch(void* const* d_in, const int* in_sizes, int n_in,
                              void* d_out, int out_size, void* d_ws, size_t ws_size,
                              hipStream_t stream) {
    (void)in_sizes; (void)n_in; (void)d_ws; (void)ws_size; (void)out_size;

    const float* query   = (const float*)d_in[0];
    const float* psi     = (const float*)d_in[1];
    const int*   knn     = (const int*)d_in[2];
    const unsigned char* mask = (const unsigned char*)d_in[3];
    const float* cur     = (const float*)d_in[4];
    const float* coords  = (const float*)d_in[5];
    const float* demands = (const float*)d_in[6];
    const float* lam_p   = (const float*)d_in[7];
    const float* mu_p    = (const float*)d_in[8];
    const float* nu_p    = (const float*)d_in[9];
    float* out = (float*)d_out;

    const long total_nodes = (long)BATCH * NP1;        // 160016
    const int  blocks = (int)((total_nodes + 3) / 4);  // 4 waves/block, 1 node/wave

    hipLaunchKernelGGL(hs_scores_kernel, dim3(blocks), dim3(256), 0, stream,
                       query, psi, knn, mask, cur, coords, demands,
                       lam_p, mu_p, nu_p, out);

    hipLaunchKernelGGL(hs_lsm_kernel, dim3(BATCH), dim3(LSM_THREADS), 0, stream, out);
}

// Round 4
// 77.491 us; speedup vs baseline: 1.6544x; 1.3853x over previous
//
#include <hip/hip_runtime.h>
#include <math.h>

// Problem constants (from setup_inputs)
#define BATCH 16
#define NP1   10001
#define KNN   16
#define DIM   128
#define NEG_INF_F (-1e9f)
#define TOTAL_NODES ((long)BATCH * NP1)             // 160016
#define SLAB_BYTES  ((size_t)BATCH * NP1 * DIM * 2) // 40,964,096 B bf16 slab

// round-to-nearest-even f32 -> bf16 (returns low 16 bits)
__device__ inline unsigned bfround(float f) {
    unsigned u = __float_as_uint(f);
    return (u + 0x7FFFu + ((u >> 16) & 1u)) >> 16;
}
// packed-bf16 pair -> f32 (no instruction risk: pure bit ops + FMA later)
__device__ inline float blo(unsigned u) { return __uint_as_float(u << 16); }
__device__ inline float bhi(unsigned u) { return __uint_as_float(u & 0xFFFF0000u); }

// ---------------------------------------------------------------------------
// Kernel A (prep): one half-wave (32 lanes) per node row.
//  - reads psi row in f32 (float4/lane, coalesced 512B)
//  - writes bf16 row to slab (uint2/lane, coalesced 256B)
//  - computes ctx = psi.q in full f32 + distance/demand epilogue
//  - writes base score to out[node]
// ---------------------------------------------------------------------------
__global__ __launch_bounds__(256) void hs_prep_kernel(
    const float* __restrict__ query,      // [B, D]
    const float* __restrict__ psi,        // [B, NP1, D]
    const float* __restrict__ cur,        // [B, 2]
    const float* __restrict__ coords,     // [B, NP1, 2]
    const float* __restrict__ demands,    // [B, NP1]
    const float* __restrict__ mu_p,
    const float* __restrict__ nu_p,
    uint2* __restrict__ slab,             // [B*NP1*32] bf16 rows
    float* __restrict__ out)              // [B, NP1] base scores
{
    const long row = (long)blockIdx.x * 8 + (threadIdx.x >> 5);
    if (row >= TOTAL_NODES) return;
    const int l32 = threadIdx.x & 31;
    const int b = (int)(row / NP1);

    const float4 v = ((const float4*)psi)[row * 32 + l32];
    const float4 q = ((const float4*)query)[(long)b * 32 + l32];

    uint2 u;
    u.x = bfround(v.x) | (bfround(v.y) << 16);
    u.y = bfround(v.z) | (bfround(v.w) << 16);
    slab[row * 32 + l32] = u;

    float ctx = v.x * q.x + v.y * q.y + v.z * q.z + v.w * q.w;
#pragma unroll
    for (int off = 16; off > 0; off >>= 1) ctx += __shfl_xor(ctx, off, 64);

    if (l32 == 0) {
        const float mu = fminf(fmaxf(mu_p[0], 0.f), 20.f);
        const float nu = fminf(fmaxf(nu_p[0], -2.f), 3.f);
        const float dx = coords[row * 2 + 0] - cur[b * 2 + 0];
        const float dy = coords[row * 2 + 1] - cur[b * 2 + 1];
        out[row] = ctx - mu * sqrtf(dx * dx + dy * dy) + nu * demands[row];
    }
}

// ---------------------------------------------------------------------------
// Kernel B (gather): 4 nodes per wave, one quarter-wave (16 lanes) per node.
// bf16 row = 256B = 16 lanes x uint4, so ONE VMEM instruction gathers 4
// different neighbor rows. All 16 gathers issued before consumption (MLP),
// consumed via bit-op bf16->f32 unpack + f32 FMA (8 independent acc chains).
// ---------------------------------------------------------------------------
__global__ __launch_bounds__(256) void hs_gather_kernel(
    const int* __restrict__ knn,            // [B, NP1, K] (int32)
    const unsigned char* __restrict__ mask, // [B, NP1]
    const uint4* __restrict__ slab4,        // bf16 rows, 16 uint4 per row
    const float* __restrict__ lam_p,
    float* __restrict__ out)                // in: base score, out: full score
{
    const int wid  = threadIdx.x >> 6;
    const int lane = threadIdx.x & 63;
    const int qw   = lane >> 4;
    const int l16  = lane & 15;
    const long node = ((long)blockIdx.x * 4 + wid) * 4 + qw;
    if (node >= TOTAL_NODES) return;
    const int b = (int)(node / NP1);
    const uint4* gb = slab4 + (long)b * NP1 * 16;   // batch slab base

    // own-row packed fragment: elements [8*l16 .. 8*l16+7], unpacked once
    const uint4 p = slab4[node * 16 + l16];
    const float pf0 = blo(p.x), pf1 = bhi(p.x);
    const float pf2 = blo(p.y), pf3 = bhi(p.y);
    const float pf4 = blo(p.z), pf5 = bhi(p.z);
    const float pf6 = blo(p.w), pf7 = bhi(p.w);

    // 16 neighbor indices (quarter-wave lanes duplicate the same 16B load)
    const int4* kp = (const int4*)(knn + node * KNN);
    const int4 k0 = kp[0], k1 = kp[1], k2 = kp[2], k3 = kp[3];

    // issue all 16 gathers (each instr fetches 4 rows, one per quarter-wave)
    uint4 nb[KNN];
    nb[ 0] = gb[(long)k0.x * 16 + l16];
    nb[ 1] = gb[(long)k0.y * 16 + l16];
    nb[ 2] = gb[(long)k0.z * 16 + l16];
    nb[ 3] = gb[(long)k0.w * 16 + l16];
    nb[ 4] = gb[(long)k1.x * 16 + l16];
    nb[ 5] = gb[(long)k1.y * 16 + l16];
    nb[ 6] = gb[(long)k1.z * 16 + l16];
    nb[ 7] = gb[(long)k1.w * 16 + l16];
    nb[ 8] = gb[(long)k2.x * 16 + l16];
    nb[ 9] = gb[(long)k2.y * 16 + l16];
    nb[10] = gb[(long)k2.z * 16 + l16];
    nb[11] = gb[(long)k2.w * 16 + l16];
    nb[12] = gb[(long)k3.x * 16 + l16];
    nb[13] = gb[(long)k3.y * 16 + l16];
    nb[14] = gb[(long)k3.z * 16 + l16];
    nb[15] = gb[(long)k3.w * 16 + l16];

    // dot-then-sum: 8 independent f32 accumulator chains, pure FMA + bit-ops
    float a0 = 0.f, a1 = 0.f, a2 = 0.f, a3 = 0.f;
    float a4 = 0.f, a5 = 0.f, a6 = 0.f, a7 = 0.f;
#pragma unroll
    for (int t = 0; t < KNN; ++t) {
        a0 = fmaf(blo(nb[t].x), pf0, a0);
        a1 = fmaf(bhi(nb[t].x), pf1, a1);
        a2 = fmaf(blo(nb[t].y), pf2, a2);
        a3 = fmaf(bhi(nb[t].y), pf3, a3);
        a4 = fmaf(blo(nb[t].z), pf4, a4);
        a5 = fmaf(bhi(nb[t].z), pf5, a5);
        a6 = fmaf(blo(nb[t].w), pf6, a6);
        a7 = fmaf(bhi(nb[t].w), pf7, a7);
    }
    float interf = ((a0 + a1) + (a2 + a3)) + ((a4 + a5) + (a6 + a7));

    // reduce across the 16-lane quarter-wave
#pragma unroll
    for (int off = 8; off > 0; off >>= 1) interf += __shfl_xor(interf, off, 64);

    if (l16 == 0) {
        const float lam = fminf(fmaxf(lam_p[0], -2.f), 3.f);
        float s = out[node] + lam * interf;
        if (mask[node]) s = NEG_INF_F;
        out[node] = s;
    }
}

// ---------------------------------------------------------------------------
// Fallback (ws too small): round-2 f32 monolithic scores kernel
// ---------------------------------------------------------------------------
__global__ __launch_bounds__(256) void hs_scores_f32_kernel(
    const float* __restrict__ query, const float* __restrict__ psi,
    const int* __restrict__ knn, const unsigned char* __restrict__ mask,
    const float* __restrict__ cur, const float* __restrict__ coords,
    const float* __restrict__ demands, const float* __restrict__ lam_p,
    const float* __restrict__ mu_p, const float* __restrict__ nu_p,
    float* __restrict__ out)
{
    const int wid  = threadIdx.x >> 6;
    const int lane = threadIdx.x & 63;
    const int half = lane >> 5;
    const int l32  = lane & 31;
    const long node = (long)blockIdx.x * 4 + wid;
    if (node >= TOTAL_NODES) return;
    const int b = (int)(node / NP1);

    const float4* psi4 = (const float4*)psi;
    const float4* gb   = psi4 + (long)b * NP1 * 32;

    const float4 p = psi4[node * 32 + l32];
    const float4 q = ((const float4*)query)[(long)b * 32 + l32];
    float ctx = p.x * q.x + p.y * q.y + p.z * q.z + p.w * q.w;

    const int2* kp2 = (const int2*)(knn + node * KNN);
    int idxs[KNN / 2];
#pragma unroll
    for (int t = 0; t < KNN / 2; ++t) {
        const int2 pr = kp2[t];
        idxs[t] = half ? pr.y : pr.x;
    }
    float4 nb[KNN / 2];
#pragma unroll
    for (int t = 0; t < KNN / 2; ++t) nb[t] = gb[(long)idxs[t] * 32 + l32];

    float4 s0;
    s0.x = ((nb[0].x + nb[1].x) + (nb[2].x + nb[3].x)) + ((nb[4].x + nb[5].x) + (nb[6].x + nb[7].x));
    s0.y = ((nb[0].y + nb[1].y) + (nb[2].y + nb[3].y)) + ((nb[4].y + nb[5].y) + (nb[6].y + nb[7].y));
    s0.z = ((nb[0].z + nb[1].z) + (nb[2].z + nb[3].z)) + ((nb[4].z + nb[5].z) + (nb[6].z + nb[7].z));
    s0.w = ((nb[0].w + nb[1].w) + (nb[2].w + nb[3].w)) + ((nb[4].w + nb[5].w) + (nb[6].w + nb[7].w));
    float interf = p.x * s0.x + p.y * s0.y + p.z * s0.z + p.w * s0.w;

#pragma unroll
    for (int off = 32; off > 0; off >>= 1) {
        ctx    += __shfl_xor(ctx, off, 64);
        interf += __shfl_xor(interf, off, 64);
    }
    if (lane == 0) {
        const float lam = fminf(fmaxf(lam_p[0], -2.f), 3.f);
        const float mu  = fminf(fmaxf(mu_p[0],   0.f), 20.f);
        const float nu  = fminf(fmaxf(nu_p[0],  -2.f), 3.f);
        const float dx = coords[node * 2 + 0] - cur[b * 2 + 0];
        const float dy = coords[node * 2 + 1] - cur[b * 2 + 1];
        float s = 0.5f * ctx + lam * interf - mu * sqrtf(dx * dx + dy * dy) + nu * demands[node];
        if (mask[node]) s = NEG_INF_F;
        out[node] = s;
    }
}

// ---------------------------------------------------------------------------
// Kernel C: in-place log_softmax per batch row (10001 elements).
// ---------------------------------------------------------------------------
#define LSM_THREADS 1024
#define LSM_ITERS   10

__global__ __launch_bounds__(LSM_THREADS) void hs_lsm_kernel(float* __restrict__ out)
{
    const int b = blockIdx.x;
    float* row = out + (long)b * NP1;
    const int lane = threadIdx.x & 63;
    const int wid  = threadIdx.x >> 6;

    float v[LSM_ITERS];
    float mx = -INFINITY;
#pragma unroll
    for (int i = 0; i < LSM_ITERS; ++i) {
        const int idx = threadIdx.x + i * LSM_THREADS;
        v[i] = (idx < NP1) ? row[idx] : -INFINITY;
        mx = fmaxf(mx, v[i]);
    }

    __shared__ float red_max[16];
    __shared__ float red_sum[16];

#pragma unroll
    for (int off = 32; off > 0; off >>= 1) mx = fmaxf(mx, __shfl_xor(mx, off, 64));
    if (lane == 0) red_max[wid] = mx;
    __syncthreads();
    if (wid == 0) {
        float m = (lane < 16) ? red_max[lane] : -INFINITY;
#pragma unroll
        for (int off = 8; off > 0; off >>= 1) m = fmaxf(m, __shfl_xor(m, off, 64));
        if (lane == 0) red_max[0] = m;
    }
    __syncthreads();
    mx = red_max[0];

    float sum = 0.f;
#pragma unroll
    for (int i = 0; i < LSM_ITERS; ++i) {
        const int idx = threadIdx.x + i * LSM_THREADS;
        if (idx < NP1) sum += expf(v[i] - mx);
    }
#pragma unroll
    for (int off = 32; off > 0; off >>= 1) sum += __shfl_xor(sum, off, 64);
    if (lane == 0) red_sum[wid] = sum;
    __syncthreads();
    if (wid == 0) {
        float s = (lane < 16) ? red_sum[lane] : 0.f;
#pragma unroll
        for (int off = 8; off > 0; off >>= 1) s += __shfl_xor(s, off, 64);
        if (lane == 0) red_sum[0] = s;
    }
    __syncthreads();
    const float lse = mx + logf(red_sum[0]);

#pragma unroll
    for (int i = 0; i < LSM_ITERS; ++i) {
        const int idx = threadIdx.x + i * LSM_THREADS;
        if (idx < NP1) row[idx] = v[i] - lse;
    }
}

// ---------------------------------------------------------------------------
extern "C" void kernel_launch(void* const* d_in, const int* in_sizes, int n_in,
                              void* d_out, int out_size, void* d_ws, size_t ws_size,
                              hipStream_t stream) {
    (void)in_sizes; (void)n_in; (void)out_size;

    const float* query   = (const float*)d_in[0];
    const float* psi     = (const float*)d_in[1];
    const int*   knn     = (const int*)d_in[2];
    const unsigned char* mask = (const unsigned char*)d_in[3];
    const float* cur     = (const float*)d_in[4];
    const float* coords  = (const float*)d_in[5];
    const float* demands = (const float*)d_in[6];
    const float* lam_p   = (const float*)d_in[7];
    const float* mu_p    = (const float*)d_in[8];
    const float* nu_p    = (const float*)d_in[9];
    float* out = (float*)d_out;

    if (ws_size >= SLAB_BYTES) {
        uint2* slab  = (uint2*)d_ws;
        const int prep_blocks = (int)((TOTAL_NODES + 7) / 8);     // 20002
        hipLaunchKernelGGL(hs_prep_kernel, dim3(prep_blocks), dim3(256), 0, stream,
                           query, psi, cur, coords, demands, mu_p, nu_p, slab, out);
        const int gat_blocks = (int)((TOTAL_NODES + 15) / 16);    // 10001
        hipLaunchKernelGGL(hs_gather_kernel, dim3(gat_blocks), dim3(256), 0, stream,
                           knn, mask, (const uint4*)d_ws, lam_p, out);
    } else {
        const int blocks = (int)((TOTAL_NODES + 3) / 4);
        hipLaunchKernelGGL(hs_scores_f32_kernel, dim3(blocks), dim3(256), 0, stream,
                           query, psi, knn, mask, cur, coords, demands,
                           lam_p, mu_p, nu_p, out);
    }
    hipLaunchKernelGGL(hs_lsm_kernel, dim3(BATCH), dim3(LSM_THREADS), 0, stream, out);
}

// Round 5
// 65.112 us; speedup vs baseline: 1.9689x; 1.1901x over previous
//
#include <hip/hip_runtime.h>
#include <math.h>

// Problem constants (from setup_inputs)
#define BATCH 16
#define NP1   10001
#define KNN   16
#define DIM   128
#define NEG_INF_F (-1e9f)
#define TOTAL_NODES ((long)BATCH * NP1)             // 160016
#define SLAB_BYTES  ((size_t)BATCH * NP1 * DIM * 2) // 40,964,096 B bf16 slab (256-aligned)
#define NXCD 8

// round-to-nearest-even f32 -> bf16 (returns low 16 bits)
__device__ inline unsigned bfround(float f) {
    unsigned u = __float_as_uint(f);
    return (u + 0x7FFFu + ((u >> 16) & 1u)) >> 16;
}
// packed-bf16 pair -> f32 (pure bit ops)
__device__ inline float blo(unsigned u) { return __uint_as_float(u << 16); }
__device__ inline float bhi(unsigned u) { return __uint_as_float(u & 0xFFFF0000u); }

// Bijective chunked XCD swizzle (m204 variant): phys block b runs on XCD b%8;
// give XCD j a contiguous chunk of logical block space so its working set is
// one batch slab (2.56MB < 4MB L2) instead of ~3.3 slabs.
__device__ inline unsigned xcd_chunk_swizzle(unsigned b, unsigned nwg) {
    const unsigned xcd = b % NXCD, i = b / NXCD;
    const unsigned q = nwg / NXCD, r = nwg % NXCD;
    const unsigned base = (xcd < r) ? xcd * (q + 1) : r * (q + 1) + (xcd - r) * q;
    return base + i;
}

// ---------------------------------------------------------------------------
// Kernel A (prep): one half-wave (32 lanes) per node row.
//  - reads psi row in f32 (float4/lane, coalesced 512B)
//  - writes bf16 row to slab (uint2/lane, coalesced 256B)
//  - computes ctx = psi.q in full f32 + distance/demand epilogue -> out
// ---------------------------------------------------------------------------
__global__ __launch_bounds__(256) void hs_prep_kernel(
    const float* __restrict__ query,      // [B, D]
    const float* __restrict__ psi,        // [B, NP1, D]
    const float* __restrict__ cur,        // [B, 2]
    const float* __restrict__ coords,     // [B, NP1, 2]
    const float* __restrict__ demands,    // [B, NP1]
    const float* __restrict__ mu_p,
    const float* __restrict__ nu_p,
    uint2* __restrict__ slab,             // [B*NP1*32] bf16 rows
    float* __restrict__ out)              // [B, NP1] base scores
{
    const unsigned lb = xcd_chunk_swizzle(blockIdx.x, gridDim.x);
    const long row = (long)lb * 8 + (threadIdx.x >> 5);
    if (row >= TOTAL_NODES) return;
    const int l32 = threadIdx.x & 31;
    const int b = (int)(row / NP1);

    const float4 v = ((const float4*)psi)[row * 32 + l32];
    const float4 q = ((const float4*)query)[(long)b * 32 + l32];

    uint2 u;
    u.x = bfround(v.x) | (bfround(v.y) << 16);
    u.y = bfround(v.z) | (bfround(v.w) << 16);
    slab[row * 32 + l32] = u;

    float ctx = v.x * q.x + v.y * q.y + v.z * q.z + v.w * q.w;
#pragma unroll
    for (int off = 16; off > 0; off >>= 1) ctx += __shfl_xor(ctx, off, 64);

    if (l32 == 0) {
        const float mu = fminf(fmaxf(mu_p[0], 0.f), 20.f);
        const float nu = fminf(fmaxf(nu_p[0], -2.f), 3.f);
        const float dx = coords[row * 2 + 0] - cur[b * 2 + 0];
        const float dy = coords[row * 2 + 1] - cur[b * 2 + 1];
        out[row] = ctx - mu * sqrtf(dx * dx + dy * dy) + nu * demands[row];
    }
}

// ---------------------------------------------------------------------------
// Kernel B (gather): 4 nodes per wave, one quarter-wave (16 lanes) per node.
// bf16 row = 256B = 16 lanes x uint4 -> ONE VMEM instruction gathers 4 rows.
// All 16 gathers issued before consumption; bit-op unpack + f32 FMA chains.
// XCD-chunked swizzle keeps each XCD inside one batch slab (L2-resident).
// ---------------------------------------------------------------------------
__global__ __launch_bounds__(256) void hs_gather_kernel(
    const int* __restrict__ knn,            // [B, NP1, K] (int32)
    const unsigned char* __restrict__ mask, // [B, NP1]
    const uint4* __restrict__ slab4,        // bf16 rows, 16 uint4 per row
    const float* __restrict__ lam_p,
    float* __restrict__ out)                // in: base score, out: full score
{
    const unsigned lb = xcd_chunk_swizzle(blockIdx.x, gridDim.x);
    const int wid  = threadIdx.x >> 6;
    const int lane = threadIdx.x & 63;
    const int qw   = lane >> 4;
    const int l16  = lane & 15;
    const long node = ((long)lb * 4 + wid) * 4 + qw;
    if (node >= TOTAL_NODES) return;
    const int b = (int)(node / NP1);
    const uint4* gb = slab4 + (long)b * NP1 * 16;   // batch slab base

    // own-row packed fragment: elements [8*l16 .. 8*l16+7], unpacked once
    const uint4 p = slab4[node * 16 + l16];
    const float pf0 = blo(p.x), pf1 = bhi(p.x);
    const float pf2 = blo(p.y), pf3 = bhi(p.y);
    const float pf4 = blo(p.z), pf5 = bhi(p.z);
    const float pf6 = blo(p.w), pf7 = bhi(p.w);

    // 16 neighbor indices (quarter-wave lanes duplicate the same 16B load)
    const int4* kp = (const int4*)(knn + node * KNN);
    const int4 k0 = kp[0], k1 = kp[1], k2 = kp[2], k3 = kp[3];

    // issue all 16 gathers (each instr fetches 4 rows, one per quarter-wave)
    uint4 nb[KNN];
    nb[ 0] = gb[(long)k0.x * 16 + l16];
    nb[ 1] = gb[(long)k0.y * 16 + l16];
    nb[ 2] = gb[(long)k0.z * 16 + l16];
    nb[ 3] = gb[(long)k0.w * 16 + l16];
    nb[ 4] = gb[(long)k1.x * 16 + l16];
    nb[ 5] = gb[(long)k1.y * 16 + l16];
    nb[ 6] = gb[(long)k1.z * 16 + l16];
    nb[ 7] = gb[(long)k1.w * 16 + l16];
    nb[ 8] = gb[(long)k2.x * 16 + l16];
    nb[ 9] = gb[(long)k2.y * 16 + l16];
    nb[10] = gb[(long)k2.z * 16 + l16];
    nb[11] = gb[(long)k2.w * 16 + l16];
    nb[12] = gb[(long)k3.x * 16 + l16];
    nb[13] = gb[(long)k3.y * 16 + l16];
    nb[14] = gb[(long)k3.z * 16 + l16];
    nb[15] = gb[(long)k3.w * 16 + l16];

    // dot-then-sum: 8 independent f32 accumulator chains
    float a0 = 0.f, a1 = 0.f, a2 = 0.f, a3 = 0.f;
    float a4 = 0.f, a5 = 0.f, a6 = 0.f, a7 = 0.f;
#pragma unroll
    for (int t = 0; t < KNN; ++t) {
        a0 = fmaf(blo(nb[t].x), pf0, a0);
        a1 = fmaf(bhi(nb[t].x), pf1, a1);
        a2 = fmaf(blo(nb[t].y), pf2, a2);
        a3 = fmaf(bhi(nb[t].y), pf3, a3);
        a4 = fmaf(blo(nb[t].z), pf4, a4);
        a5 = fmaf(bhi(nb[t].z), pf5, a5);
        a6 = fmaf(blo(nb[t].w), pf6, a6);
        a7 = fmaf(bhi(nb[t].w), pf7, a7);
    }
    float interf = ((a0 + a1) + (a2 + a3)) + ((a4 + a5) + (a6 + a7));

    // reduce across the 16-lane quarter-wave
#pragma unroll
    for (int off = 8; off > 0; off >>= 1) interf += __shfl_xor(interf, off, 64);

    if (l16 == 0) {
        const float lam = fminf(fmaxf(lam_p[0], -2.f), 3.f);
        float s = out[node] + lam * interf;
        if (mask[node]) s = NEG_INF_F;
        out[node] = s;
    }
}

// ---------------------------------------------------------------------------
// Fallback (ws too small): round-2 f32 monolithic scores kernel
// ---------------------------------------------------------------------------
__global__ __launch_bounds__(256) void hs_scores_f32_kernel(
    const float* __restrict__ query, const float* __restrict__ psi,
    const int* __restrict__ knn, const unsigned char* __restrict__ mask,
    const float* __restrict__ cur, const float* __restrict__ coords,
    const float* __restrict__ demands, const float* __restrict__ lam_p,
    const float* __restrict__ mu_p, const float* __restrict__ nu_p,
    float* __restrict__ out)
{
    const int wid  = threadIdx.x >> 6;
    const int lane = threadIdx.x & 63;
    const int half = lane >> 5;
    const int l32  = lane & 31;
    const long node = (long)blockIdx.x * 4 + wid;
    if (node >= TOTAL_NODES) return;
    const int b = (int)(node / NP1);

    const float4* psi4 = (const float4*)psi;
    const float4* gb   = psi4 + (long)b * NP1 * 32;

    const float4 p = psi4[node * 32 + l32];
    const float4 q = ((const float4*)query)[(long)b * 32 + l32];
    float ctx = p.x * q.x + p.y * q.y + p.z * q.z + p.w * q.w;

    const int2* kp2 = (const int2*)(knn + node * KNN);
    int idxs[KNN / 2];
#pragma unroll
    for (int t = 0; t < KNN / 2; ++t) {
        const int2 pr = kp2[t];
        idxs[t] = half ? pr.y : pr.x;
    }
    float4 nb[KNN / 2];
#pragma unroll
    for (int t = 0; t < KNN / 2; ++t) nb[t] = gb[(long)idxs[t] * 32 + l32];

    float4 s0;
    s0.x = ((nb[0].x + nb[1].x) + (nb[2].x + nb[3].x)) + ((nb[4].x + nb[5].x) + (nb[6].x + nb[7].x));
    s0.y = ((nb[0].y + nb[1].y) + (nb[2].y + nb[3].y)) + ((nb[4].y + nb[5].y) + (nb[6].y + nb[7].y));
    s0.z = ((nb[0].z + nb[1].z) + (nb[2].z + nb[3].z)) + ((nb[4].z + nb[5].z) + (nb[6].z + nb[7].z));
    s0.w = ((nb[0].w + nb[1].w) + (nb[2].w + nb[3].w)) + ((nb[4].w + nb[5].w) + (nb[6].w + nb[7].w));
    float interf = p.x * s0.x + p.y * s0.y + p.z * s0.z + p.w * s0.w;

#pragma unroll
    for (int off = 32; off > 0; off >>= 1) {
        ctx    += __shfl_xor(ctx, off, 64);
        interf += __shfl_xor(interf, off, 64);
    }
    if (lane == 0) {
        const float lam = fminf(fmaxf(lam_p[0], -2.f), 3.f);
        const float mu  = fminf(fmaxf(mu_p[0],   0.f), 20.f);
        const float nu  = fminf(fmaxf(nu_p[0],  -2.f), 3.f);
        const float dx = coords[node * 2 + 0] - cur[b * 2 + 0];
        const float dy = coords[node * 2 + 1] - cur[b * 2 + 1];
        float s = 0.5f * ctx + lam * interf - mu * sqrtf(dx * dx + dy * dy) + nu * demands[node];
        if (mask[node]) s = NEG_INF_F;
        out[node] = s;
    }
}

// ---------------------------------------------------------------------------
// Split log-softmax: 4 blocks per batch row (64 blocks total).
// K1: per-quarter {max, sumexp(local max)} -> ws partials
// K2: combine partials online, write v - lse over the quarter.
// ---------------------------------------------------------------------------
#define LSM_SPLIT 4
#define LSM_Q ((NP1 + LSM_SPLIT - 1) / LSM_SPLIT)   // 2501
#define LSM_T 1024

__device__ inline float block_reduce_max(float v, float* red) {
    const int lane = threadIdx.x & 63, wid = threadIdx.x >> 6;
#pragma unroll
    for (int off = 32; off > 0; off >>= 1) v = fmaxf(v, __shfl_xor(v, off, 64));
    if (lane == 0) red[wid] = v;
    __syncthreads();
    if (wid == 0) {
        float m = (lane < LSM_T / 64) ? red[lane] : -INFINITY;
#pragma unroll
        for (int off = 8; off > 0; off >>= 1) m = fmaxf(m, __shfl_xor(m, off, 64));
        if (lane == 0) red[0] = m;
    }
    __syncthreads();
    return red[0];
}
__device__ inline float block_reduce_sum(float v, float* red) {
    const int lane = threadIdx.x & 63, wid = threadIdx.x >> 6;
#pragma unroll
    for (int off = 32; off > 0; off >>= 1) v += __shfl_xor(v, off, 64);
    if (lane == 0) red[wid] = v;
    __syncthreads();
    if (wid == 0) {
        float s = (lane < LSM_T / 64) ? red[lane] : 0.f;
#pragma unroll
        for (int off = 8; off > 0; off >>= 1) s += __shfl_xor(s, off, 64);
        if (lane == 0) red[0] = s;
    }
    __syncthreads();
    return red[0];
}

__global__ __launch_bounds__(LSM_T) void hs_lsm_part1(
    const float* __restrict__ out, float* __restrict__ partials)
{
    const int b = blockIdx.x / LSM_SPLIT, qd = blockIdx.x % LSM_SPLIT;
    const int start = qd * LSM_Q;
    const int end   = (start + LSM_Q < NP1) ? start + LSM_Q : NP1;
    const float* row = out + (long)b * NP1;
    __shared__ float red[LSM_T / 64];

    float v[3];
    float mx = -INFINITY;
#pragma unroll
    for (int i = 0; i < 3; ++i) {
        const int idx = start + threadIdx.x + i * LSM_T;
        v[i] = (idx < end) ? row[idx] : -INFINITY;
        mx = fmaxf(mx, v[i]);
    }
    mx = block_reduce_max(mx, red);
    __syncthreads();
    float sum = 0.f;
#pragma unroll
    for (int i = 0; i < 3; ++i) sum += (v[i] > -INFINITY) ? expf(v[i] - mx) : 0.f;
    sum = block_reduce_sum(sum, red);
    if (threadIdx.x == 0) {
        partials[2 * blockIdx.x]     = mx;
        partials[2 * blockIdx.x + 1] = sum;
    }
}

__global__ __launch_bounds__(LSM_T) void hs_lsm_part2(
    float* __restrict__ out, const float* __restrict__ partials)
{
    const int b = blockIdx.x / LSM_SPLIT, qd = blockIdx.x % LSM_SPLIT;
    const int start = qd * LSM_Q;
    const int end   = (start + LSM_Q < NP1) ? start + LSM_Q : NP1;
    float* row = out + (long)b * NP1;

    // online combine of the row's 4 partials (redundant per-thread, cheap)
    float m = -INFINITY, s = 0.f;
#pragma unroll
    for (int j = 0; j < LSM_SPLIT; ++j) {
        const float mj = partials[2 * (b * LSM_SPLIT + j)];
        const float sj = partials[2 * (b * LSM_SPLIT + j) + 1];
        if (mj > m) { s = s * expf(m - mj) + sj; m = mj; }
        else        { s += sj * expf(mj - m); }
    }
    const float lse = m + logf(s);
#pragma unroll
    for (int i = 0; i < 3; ++i) {
        const int idx = start + threadIdx.x + i * LSM_T;
        if (idx < end) row[idx] -= lse;
    }
}

// Fallback single-kernel lsm (no workspace use)
__global__ __launch_bounds__(LSM_T) void hs_lsm_kernel(float* __restrict__ out)
{
    const int b = blockIdx.x;
    float* row = out + (long)b * NP1;
    __shared__ float red[LSM_T / 64];
    float v[10];
    float mx = -INFINITY;
#pragma unroll
    for (int i = 0; i < 10; ++i) {
        const int idx = threadIdx.x + i * LSM_T;
        v[i] = (idx < NP1) ? row[idx] : -INFINITY;
        mx = fmaxf(mx, v[i]);
    }
    mx = block_reduce_max(mx, red);
    __syncthreads();
    float sum = 0.f;
#pragma unroll
    for (int i = 0; i < 10; ++i) {
        const int idx = threadIdx.x + i * LSM_T;
        if (idx < NP1) sum += expf(v[i] - mx);
    }
    sum = block_reduce_sum(sum, red);
    const float lse = mx + logf(sum);
#pragma unroll
    for (int i = 0; i < 10; ++i) {
        const int idx = threadIdx.x + i * LSM_T;
        if (idx < NP1) row[idx] = v[i] - lse;
    }
}

// ---------------------------------------------------------------------------
extern "C" void kernel_launch(void* const* d_in, const int* in_sizes, int n_in,
                              void* d_out, int out_size, void* d_ws, size_t ws_size,
                              hipStream_t stream) {
    (void)in_sizes; (void)n_in; (void)out_size;

    const float* query   = (const float*)d_in[0];
    const float* psi     = (const float*)d_in[1];
    const int*   knn     = (const int*)d_in[2];
    const unsigned char* mask = (const unsigned char*)d_in[3];
    const float* cur     = (const float*)d_in[4];
    const float* coords  = (const float*)d_in[5];
    const float* demands = (const float*)d_in[6];
    const float* lam_p   = (const float*)d_in[7];
    const float* mu_p    = (const float*)d_in[8];
    const float* nu_p    = (const float*)d_in[9];
    float* out = (float*)d_out;

    const size_t partials_bytes = (size_t)BATCH * LSM_SPLIT * 2 * sizeof(float); // 512B

    if (ws_size >= SLAB_BYTES) {
        uint2* slab = (uint2*)d_ws;
        const int prep_blocks = (int)((TOTAL_NODES + 7) / 8);     // 20002
        hipLaunchKernelGGL(hs_prep_kernel, dim3(prep_blocks), dim3(256), 0, stream,
                           query, psi, cur, coords, demands, mu_p, nu_p, slab, out);
        const int gat_blocks = (int)((TOTAL_NODES + 15) / 16);    // 10001
        hipLaunchKernelGGL(hs_gather_kernel, dim3(gat_blocks), dim3(256), 0, stream,
                           knn, mask, (const uint4*)d_ws, lam_p, out);
        if (ws_size >= SLAB_BYTES + partials_bytes) {
            float* partials = (float*)((char*)d_ws + SLAB_BYTES);
            hipLaunchKernelGGL(hs_lsm_part1, dim3(BATCH * LSM_SPLIT), dim3(LSM_T), 0, stream,
                               out, partials);
            hipLaunchKernelGGL(hs_lsm_part2, dim3(BATCH * LSM_SPLIT), dim3(LSM_T), 0, stream,
                               out, partials);
        } else {
            hipLaunchKernelGGL(hs_lsm_kernel, dim3(BATCH), dim3(LSM_T), 0, stream, out);
        }
    } else {
        const int blocks = (int)((TOTAL_NODES + 3) / 4);
        hipLaunchKernelGGL(hs_scores_f32_kernel, dim3(blocks), dim3(256), 0, stream,
                           query, psi, knn, mask, cur, coords, demands,
                           lam_p, mu_p, nu_p, out);
        hipLaunchKernelGGL(hs_lsm_kernel, dim3(BATCH), dim3(LSM_T), 0, stream, out);
    }
}